// Round 9
// baseline (214.562 us; speedup 1.0000x reference)
//
#include <hip/hip_runtime.h>

#define TPB 512
#define NW 8
#define NPTS 2000
#define M1C 100
#define M2C 5
#define KNN 20
#define CANDCAP 128

// Bitwise-exact squared distance matching numpy fp32 sequential sum:
// ((dx*dx + dy*dy) + dz*dz), no FMA contraction.
__device__ __forceinline__ float dist3(float px, float py, float pz,
                                       float qx, float qy, float qz) {
#pragma clang fp contract(off)
    float dx = px - qx, dy = py - qy, dz = pz - qz;
    return dx * dx + dy * dy + dz * dz;
}

// Fused wave64 (value,index) argmax, min-index tie-break, DPP chain.
#define ARGMAX_STEP(ctrl, rm)                                                        \
    do {                                                                             \
        float ov = __int_as_float(__builtin_amdgcn_update_dpp(                       \
            (int)0xff800000, __float_as_int(v), ctrl, rm, 0xf, false));              \
        int oi = __builtin_amdgcn_update_dpp(0x7fffffff, i, ctrl, rm, 0xf, false);   \
        bool take = (ov > v) || (ov == v && oi < i);                                 \
        v = take ? ov : v;                                                           \
        i = take ? oi : i;                                                           \
    } while (0)

__device__ __forceinline__ void wave_argmax(float& v, int& i) {
    ARGMAX_STEP(0x111, 0xf);
    ARGMAX_STEP(0x112, 0xf);
    ARGMAX_STEP(0x114, 0xf);
    ARGMAX_STEP(0x118, 0xf);
    ARGMAX_STEP(0x142, 0xa);
    ARGMAX_STEP(0x143, 0xc);
    v = __int_as_float(__builtin_amdgcn_readlane(__float_as_int(v), 63));
    i = __builtin_amdgcn_readlane(i, 63);
}

#define FMAX_STEP(ctrl, rm)                                                          \
    do {                                                                             \
        float _t = __int_as_float(__builtin_amdgcn_update_dpp(                       \
            (int)0xff800000, __float_as_int(x), ctrl, rm, 0xf, false));              \
        x = fmaxf(x, _t);                                                            \
    } while (0)

__device__ __forceinline__ float wave_fmax(float x) {
    FMAX_STEP(0x111, 0xf);
    FMAX_STEP(0x112, 0xf);
    FMAX_STEP(0x114, 0xf);
    FMAX_STEP(0x118, 0xf);
    FMAX_STEP(0x142, 0xa);
    FMAX_STEP(0x143, 0xc);
    return __int_as_float(__builtin_amdgcn_readlane(__float_as_int(x), 63));
}

// ============ Fused kernel: FPS producers + knn1/MLP1 consumers + tail ============
// Points live in REGISTERS (producers) and L1-hot GLOBAL (consumers) — no LDS
// point array at all; FPS-loop LDS traffic is just the 4-slot exchange + flags.
__global__ __launch_bounds__(TPB, 2) void fused_kernel(
    const float* __restrict__ P,
    const float* __restrict__ W1, const float* __restrict__ b1,
    const float* __restrict__ W2, const float* __restrict__ b2,
    const float* __restrict__ W3, const float* __restrict__ b3,
    const float* __restrict__ D1, const float* __restrict__ bD1,
    const float* __restrict__ D2, const float* __restrict__ bD2,
    const float* __restrict__ D3, const float* __restrict__ bD3,
    float* __restrict__ out)
{
    __shared__ float smpx[M1C], smpy[M1C], smpz[M1C];
    __shared__ float s2x[M2C], s2y[M2C], s2z[M2C];
    __shared__ float f1s[M1C][5];
    __shared__ float knd[NW][CANDCAP];
    __shared__ int   kni[NW][CANDCAP];
    __shared__ __align__(16) float4 sA[2][4];
    __shared__ __align__(16) float  sZ[2][4];
    __shared__ int flags[4];               // flags[w] = #iterations wave w completed
    __shared__ float f2s[M2C][25];
    __shared__ float latent[45];
    __shared__ float decv[M2C][3];
    __shared__ float cfs[M2C][25];
    __shared__ float dec2s[M1C][3];
    __shared__ float cf2s[M1C][5];
    __shared__ float w2s[200], b2s[25], w3s[1260], b3s[45];

    const int b = blockIdx.x;
    const int tid = threadIdx.x;
    const int lane = tid & 63;
    const int wid = tid >> 6;

    const float R1SQ = (float)(0.3 * 0.3);   // f64 product then cast
    const float R2SQ = 1.0f;
    const float INVR1 = 1.0f / 0.3f;

    const float* Pb = P + (size_t)b * (NPTS * 3);

    // ---- stage small weights only ----
    for (int t = tid; t < 200; t += TPB) w2s[t] = W2[t];
    for (int t = tid; t < 25; t += TPB) b2s[t] = b2[t];
    for (int t = tid; t < 1260; t += TPB) w3s[t] = W3[t];
    for (int t = tid; t < 45; t += TPB) b3s[t] = b3[t];
    if (tid < 4) flags[tid] = 0;
    __syncthreads();

    if (wid < 4) {
        // ================= producers: FPS1 (waves 0-3, tid 0..255) =================
        __builtin_amdgcn_s_setprio(3);
        float px[8], py[8], pz[8], mind[8];
#pragma unroll
        for (int k = 0; k < 8; ++k) {
            int j = tid + (k << 8);
            bool v = j < NPTS;
            int jc = v ? j : 0;
            px[k] = v ? Pb[3 * jc + 0] : 1e18f;
            py[k] = v ? Pb[3 * jc + 1] : 1e18f;
            pz[k] = v ? Pb[3 * jc + 2] : 1e18f;
            mind[k] = v ? 1e10f : -1.0f;
        }

        float qx = Pb[0], qy = Pb[1], qz = Pb[2];
        for (int it = 0; it < M1C; ++it) {
            if (tid == 0) { smpx[it] = qx; smpy[it] = qy; smpz[it] = qz; }
            float m[8];
#pragma unroll
            for (int k = 0; k < 8; ++k) {
                float d = dist3(px[k], py[k], pz[k], qx, qy, qz);
                m[k] = fminf(mind[k], d);
                mind[k] = m[k];
            }
            // tree argmax over 8 chunks; strict > keeps lowest chunk on ties
            float va = m[0]; int ka = 0; if (m[1] > va) { va = m[1]; ka = 1; }
            float vb = m[2]; int kb = 2; if (m[3] > vb) { vb = m[3]; kb = 3; }
            float vc = m[4]; int kc = 4; if (m[5] > vc) { vc = m[5]; kc = 5; }
            float vd = m[6]; int kd = 6; if (m[7] > vd) { vd = m[7]; kd = 7; }
            if (vb > va) { va = vb; ka = kb; }
            if (vd > vc) { vc = vd; kc = kd; }
            if (vc > va) { va = vc; ka = kc; }
            float bv = va; int bi = tid + (ka << 8);
            if (it == M1C - 1) {
                if (lane == 0)
                    __hip_atomic_store(&flags[wid], M1C, __ATOMIC_RELEASE,
                                       __HIP_MEMORY_SCOPE_WORKGROUP);
                break;
            }
            float lv = bv; int li = bi;
            wave_argmax(bv, bi);
            int p = it & 1;
            if (lv == bv && li == bi) {            // unique winner lane per wave
                int k = bi >> 8;
                float cx = px[0], cy = py[0], cz = pz[0];
#pragma unroll
                for (int kk = 1; kk < 8; ++kk) {
                    bool t = (k == kk);
                    cx = t ? px[kk] : cx;
                    cy = t ? py[kk] : cy;
                    cz = t ? pz[kk] : cz;
                }
                sA[p][wid] = make_float4(bv, __int_as_float(bi), cx, cy);
                sZ[p][wid] = cz;
            }
            if (lane == 0)
                __hip_atomic_store(&flags[wid], it + 1, __ATOMIC_RELEASE,
                                   __HIP_MEMORY_SCOPE_WORKGROUP);
            // tight spin (priority 3): wait all 4 producer waves posted
            for (;;) {
                int f = 0x7fffffff;
                if (lane < 4)
                    f = __hip_atomic_load(&flags[lane], __ATOMIC_ACQUIRE,
                                          __HIP_MEMORY_SCOPE_WORKGROUP);
                if (__ballot(f >= it + 1) == ~0ull) break;
            }
            float4 a0 = sA[p][0], a1 = sA[p][1], a2 = sA[p][2], a3 = sA[p][3];
            float4 z0 = *(const float4*)&sZ[p][0];
            // tree combine, min-index ties
            float cv0 = a0.x; int ci0 = __float_as_int(a0.y);
            float x0 = a0.z, y0 = a0.w, zz0 = z0.x;
            {
                int ii = __float_as_int(a1.y);
                bool t = (a1.x > cv0) || (a1.x == cv0 && ii < ci0);
                if (t) { cv0 = a1.x; ci0 = ii; x0 = a1.z; y0 = a1.w; zz0 = z0.y; }
            }
            float cv1 = a2.x; int ci1 = __float_as_int(a2.y);
            float x1 = a2.z, y1 = a2.w, zz1 = z0.z;
            {
                int ii = __float_as_int(a3.y);
                bool t = (a3.x > cv1) || (a3.x == cv1 && ii < ci1);
                if (t) { cv1 = a3.x; ci1 = ii; x1 = a3.z; y1 = a3.w; zz1 = z0.w; }
            }
            bool t = (cv1 > cv0) || (cv1 == cv0 && ci1 < ci0);
            qx = t ? x1 : x0; qy = t ? y1 : y0; qz = t ? zz1 : zz0;
        }

        if (wid == 0) {
            // ---- FPS2: 5 from 100 (single wave, in-LDS smp) ----
            float ax = smpx[lane], ay = smpy[lane], az = smpz[lane];
            bool vb2 = lane < (M1C - 64);
            float bx2 = vb2 ? smpx[lane + 64] : 1e18f;
            float by2 = vb2 ? smpy[lane + 64] : 1e18f;
            float bz2 = vb2 ? smpz[lane + 64] : 1e18f;
            float m2a = 1e10f;
            float m2b = vb2 ? 1e10f : -1.0f;
            int last2 = 0;
            for (int it = 0; it < M2C; ++it) {
                float fx = smpx[last2], fy = smpy[last2], fz = smpz[last2];
                if (lane == 0) { s2x[it] = fx; s2y[it] = fy; s2z[it] = fz; }
                m2a = fminf(m2a, dist3(ax, ay, az, fx, fy, fz));
                m2b = fminf(m2b, dist3(bx2, by2, bz2, fx, fy, fz));
                float v = m2a; int i = lane;
                if (m2b > v) { v = m2b; i = lane + 64; }
                wave_argmax(v, i);
                last2 = i;
            }
        }
        __builtin_amdgcn_s_setprio(0);
    } else {
        // ========= consumers: knn1 + MLP1 (waves 4-7), points from global/L1 =========
        __builtin_amdgcn_s_setprio(0);
        float rw1[15], rb1[5];
#pragma unroll
        for (int i = 0; i < 15; ++i) rw1[i] = W1[i];
#pragma unroll
        for (int i = 0; i < 5; ++i) rb1[i] = b1[i];

        for (int s = wid - 4; s < M1C; s += 4) {
            // wait until producer wave 0 has published smp[s]
            while (__hip_atomic_load(&flags[0], __ATOMIC_ACQUIRE,
                                     __HIP_MEMORY_SCOPE_WORKGROUP) <= s)
                __builtin_amdgcn_s_sleep(2);
            float qx = smpx[s], qy = smpy[s], qz = smpz[s];
            int cn = 0;
#pragma unroll 4
            for (int c = 0; c < 32; ++c) {
                int j = c * 64 + lane;
                float d = 0.0f; bool pred = false;
                if (j < NPTS) {
                    d = dist3(Pb[3 * j], Pb[3 * j + 1], Pb[3 * j + 2], qx, qy, qz);
                    pred = (d <= R1SQ);
                }
                unsigned long long mb = __ballot(pred);
                if (pred) {
                    int pos = cn + (int)__popcll(mb & ((1ull << lane) - 1ull));
                    if (pos < CANDCAP) { knd[wid][pos] = d; kni[wid][pos] = j; }
                }
                cn += (int)__popcll(mb);
            }
            if (cn > CANDCAP) cn = CANDCAP;  // P(Poisson λ≈14 > 128) ~ 1e-68
            float fmx[5];
#pragma unroll
            for (int f = 0; f < 5; ++f) fmx[f] = -1e30f;
            for (int t = lane; t < cn; t += 64) {
                float d = knd[wid][t]; int j = kni[wid][t];
                bool valid = true;
                if (cn > KNN) {
                    int rank = 0;
                    for (int u = 0; u < cn; ++u) {
                        float du = knd[wid][u]; int iu = kni[wid][u];
                        rank += (du < d || (du == d && iu < j)) ? 1 : 0;
                    }
                    valid = rank < KNN;   // replicates top_k stability (ties -> lower idx)
                }
                if (valid) {
                    float rx = (Pb[3 * j] - qx) * INVR1;
                    float ry = (Pb[3 * j + 1] - qy) * INVR1;
                    float rz = (Pb[3 * j + 2] - qz) * INVR1;
#pragma unroll
                    for (int f = 0; f < 5; ++f) {
                        float h = fmaf(rx, rw1[f], fmaf(ry, rw1[5 + f], fmaf(rz, rw1[10 + f], rb1[f])));
                        fmx[f] = fmaxf(fmx[f], fmaxf(h, 0.0f));
                    }
                }
            }
#pragma unroll
            for (int f = 0; f < 5; ++f) fmx[f] = wave_fmax(fmx[f]);
            if (lane == 0) {
#pragma unroll
                for (int f = 0; f < 5; ++f) f1s[s][f] = fmx[f];
            }
        }
    }
    __syncthreads();   // all 8 waves reach exactly once

    // ================= tail: knn2 + MLP2, MLP3, decoder =================
    for (int s = wid; s < M2C; s += NW) {
        float qx2 = s2x[s], qy2 = s2y[s], qz2 = s2z[s];
        int cn = 0;
#pragma unroll
        for (int c = 0; c < 2; ++c) {
            int j = c * 64 + lane;
            float d = 0.0f; bool pred = false;
            if (j < M1C) {
                d = dist3(smpx[j], smpy[j], smpz[j], qx2, qy2, qz2);
                pred = (d <= R2SQ);
            }
            unsigned long long mb = __ballot(pred);
            if (pred) {
                int pos = cn + (int)__popcll(mb & ((1ull << lane) - 1ull));
                knd[wid][pos] = d; kni[wid][pos] = j;   // cn<=100<CANDCAP
            }
            cn += (int)__popcll(mb);
        }
        float hmx[25];
#pragma unroll
        for (int f = 0; f < 25; ++f) hmx[f] = -1e30f;
        for (int t = lane; t < cn; t += 64) {
            float d = knd[wid][t]; int j = kni[wid][t];
            bool valid = true;
            if (cn > KNN) {
                int rank = 0;
                for (int u = 0; u < cn; ++u) {
                    float du = knd[wid][u]; int iu = kni[wid][u];
                    rank += (du < d || (du == d && iu < j)) ? 1 : 0;
                }
                valid = rank < KNN;
            }
            if (valid) {
                float in8[8];
                in8[0] = smpx[j] - qx2; in8[1] = smpy[j] - qy2; in8[2] = smpz[j] - qz2;
#pragma unroll
                for (int f = 0; f < 5; ++f) in8[3 + f] = f1s[j][f];
#pragma unroll
                for (int f = 0; f < 25; ++f) {
                    float h = b2s[f];
#pragma unroll
                    for (int i = 0; i < 8; ++i) h = fmaf(in8[i], w2s[i * 25 + f], h);
                    hmx[f] = fmaxf(hmx[f], fmaxf(h, 0.0f));
                }
            }
        }
#pragma unroll
        for (int f = 0; f < 25; ++f) {
            float mx = wave_fmax(hmx[f]);
            if (lane == 0) f2s[s][f] = mx;
        }
    }
    __syncthreads();

    // ---- MLP3 + max-pool -> latent (45) ----
    if (wid == 0 && lane < 45) {
        float lm = -1e30f;
        for (int r = 0; r < M2C; ++r) {
            float h = b3s[lane];
            h = fmaf(s2x[r] * 0.5f, w3s[0 * 45 + lane], h);
            h = fmaf(s2y[r] * 0.5f, w3s[1 * 45 + lane], h);
            h = fmaf(s2z[r] * 0.5f, w3s[2 * 45 + lane], h);
#pragma unroll
            for (int i = 0; i < 25; ++i) h = fmaf(f2s[r][i], w3s[(3 + i) * 45 + lane], h);
            lm = fmaxf(lm, fmaxf(h, 0.0f));
        }
        latent[lane] = lm;
    }
    __syncthreads();

    // ---- decoder stage 1: latent @ D1 + bD1 -> (5, 28) ----
    for (int t = tid; t < 140; t += TPB) {
        float acc = bD1[t];
        for (int i = 0; i < 45; i++) acc = fmaf(latent[i], D1[i * 140 + t], acc);
        int r = t / 28, c = t % 28;
        if (c < 3) decv[r][c] = acc;
        else cfs[r][c - 3] = fmaxf(acc, 0.0f);
    }
    __syncthreads();

    // ---- decoder stage 2: cf @ D2 + bD2 -> (100, 8) ----
    for (int t = tid; t < 800; t += TPB) {
        int r = t / 160, c = t % 160;
        float acc = bD2[c];
        for (int i = 0; i < 25; i++) acc = fmaf(cfs[r][i], D2[i * 160 + c], acc);
        int g = r * 20 + c / 8, c8 = c % 8;
        if (c8 < 3) dec2s[g][c8] = acc;
        else cf2s[g][c8 - 3] = fmaxf(acc, 0.0f);
    }
    __syncthreads();

    // ---- decoder stage 3 + compose output ----
    float* outb = out + (size_t)b * (NPTS * 3);
    for (int t = tid; t < NPTS * 3; t += TPB) {
        int n = t / 3, c = t % 3;
        int g = n / 20;
        int m = n / 400;
        int r60 = (n % 20) * 3 + c;
        float acc = bD3[r60];
        for (int i = 0; i < 5; i++) acc = fmaf(cf2s[g][i], D3[i * 60 + r60], acc);
        // out = ((dec*R3 + dec2)*R2 + dec3)*R1, R2 = 1
        float val = ((decv[m][c] * 2.0f + dec2s[g][c]) + acc) * 0.3f;
        outb[t] = val;
    }
}

extern "C" void kernel_launch(void* const* d_in, const int* in_sizes, int n_in,
                              void* d_out, int out_size, void* d_ws, size_t ws_size,
                              hipStream_t stream) {
    const float* P   = (const float*)d_in[0];
    const float* W1  = (const float*)d_in[1];
    const float* b1  = (const float*)d_in[2];
    const float* W2  = (const float*)d_in[3];
    const float* b2  = (const float*)d_in[4];
    const float* W3  = (const float*)d_in[5];
    const float* b3  = (const float*)d_in[6];
    const float* D1  = (const float*)d_in[7];
    const float* bD1 = (const float*)d_in[8];
    const float* D2  = (const float*)d_in[9];
    const float* bD2 = (const float*)d_in[10];
    const float* D3  = (const float*)d_in[11];
    const float* bD3 = (const float*)d_in[12];
    float* out = (float*)d_out;

    int B = in_sizes[0] / (NPTS * 3);
    hipLaunchKernelGGL(fused_kernel, dim3(B), dim3(TPB), 0, stream,
                       P, W1, b1, W2, b2, W3, b3, D1, bD1, D2, bD2, D3, bD3, out);
}

// Round 10
// 192.708 us; speedup vs baseline: 1.1134x; 1.1134x over previous
//
#include <hip/hip_runtime.h>

#define TPB 512
#define NW 8
#define NPTS 2000
#define M1C 100
#define M2C 5
#define KNN 20
#define CANDCAP 128

// Bitwise-exact squared distance matching numpy fp32 sequential sum:
// ((dx*dx + dy*dy) + dz*dz), no FMA contraction.
__device__ __forceinline__ float dist3(float px, float py, float pz,
                                       float qx, float qy, float qz) {
#pragma clang fp contract(off)
    float dx = px - qx, dy = py - qy, dz = pz - qz;
    return dx * dx + dy * dy + dz * dz;
}

// Fused wave64 (value,index) argmax, min-index tie-break, DPP chain.
#define ARGMAX_STEP(ctrl, rm)                                                        \
    do {                                                                             \
        float ov = __int_as_float(__builtin_amdgcn_update_dpp(                       \
            (int)0xff800000, __float_as_int(v), ctrl, rm, 0xf, false));              \
        int oi = __builtin_amdgcn_update_dpp(0x7fffffff, i, ctrl, rm, 0xf, false);   \
        bool take = (ov > v) || (ov == v && oi < i);                                 \
        v = take ? ov : v;                                                           \
        i = take ? oi : i;                                                           \
    } while (0)

__device__ __forceinline__ void wave_argmax(float& v, int& i) {
    ARGMAX_STEP(0x111, 0xf);
    ARGMAX_STEP(0x112, 0xf);
    ARGMAX_STEP(0x114, 0xf);
    ARGMAX_STEP(0x118, 0xf);
    ARGMAX_STEP(0x142, 0xa);
    ARGMAX_STEP(0x143, 0xc);
    v = __int_as_float(__builtin_amdgcn_readlane(__float_as_int(v), 63));
    i = __builtin_amdgcn_readlane(i, 63);
}

#define FMAX_STEP(ctrl, rm)                                                          \
    do {                                                                             \
        float _t = __int_as_float(__builtin_amdgcn_update_dpp(                       \
            (int)0xff800000, __float_as_int(x), ctrl, rm, 0xf, false));              \
        x = fmaxf(x, _t);                                                            \
    } while (0)

__device__ __forceinline__ float wave_fmax(float x) {
    FMAX_STEP(0x111, 0xf);
    FMAX_STEP(0x112, 0xf);
    FMAX_STEP(0x114, 0xf);
    FMAX_STEP(0x118, 0xf);
    FMAX_STEP(0x142, 0xa);
    FMAX_STEP(0x143, 0xc);
    return __int_as_float(__builtin_amdgcn_readlane(__float_as_int(x), 63));
}

// ============ Fused kernel: FPS producers + knn1/MLP1 consumers + tail ============
// R10 = R7 (best, 136us) + conflict-free staging + tree reduces + DPP-free knn2.
__global__ __launch_bounds__(TPB, 2) void fused_kernel(
    const float* __restrict__ P,
    const float* __restrict__ W1, const float* __restrict__ b1,
    const float* __restrict__ W2, const float* __restrict__ b2,
    const float* __restrict__ W3, const float* __restrict__ b3,
    const float* __restrict__ D1, const float* __restrict__ bD1,
    const float* __restrict__ D2, const float* __restrict__ bD2,
    const float* __restrict__ D3, const float* __restrict__ bD3,
    float* __restrict__ out)
{
    __shared__ float sx[NPTS], sy[NPTS], sz[NPTS];
    __shared__ float smpx[M1C], smpy[M1C], smpz[M1C];
    __shared__ float s2x[M2C], s2y[M2C], s2z[M2C];
    __shared__ float f1s[M1C][5];
    __shared__ float knd[NW][CANDCAP];
    __shared__ int   kni[NW][CANDCAP];
    __shared__ float vin[M2C][KNN][8];     // knn2 valid-candidate inputs
    __shared__ __align__(16) float4 sA[2][4];
    __shared__ __align__(16) float  sZ[2][4];
    __shared__ int flags[4];               // flags[w] = #iterations wave w completed
    __shared__ float f2s[M2C][25];
    __shared__ float latent[45];
    __shared__ float decv[M2C][3];
    __shared__ float cfs[M2C][25];
    __shared__ float dec2s[M1C][3];
    __shared__ float cf2s[M1C][5];
    __shared__ float w2s[200], b2s[25], w3s[1260], b3s[45];

    const int b = blockIdx.x;
    const int tid = threadIdx.x;
    const int lane = tid & 63;
    const int wid = tid >> 6;

    const float R1SQ = (float)(0.3 * 0.3);   // f64 product then cast
    const float R2SQ = 1.0f;
    const float INVR1 = 1.0f / 0.3f;

    // ---- staging (all 8 waves): conflict-free stride-1 LDS writes ----
    const float* Pb = P + (size_t)b * (NPTS * 3);
    for (int j = tid; j < NPTS; j += TPB) {
        sx[j] = Pb[3 * j + 0];
        sy[j] = Pb[3 * j + 1];
        sz[j] = Pb[3 * j + 2];
    }
    for (int t = tid; t < 200; t += TPB) w2s[t] = W2[t];
    for (int t = tid; t < 25; t += TPB) b2s[t] = b2[t];
    for (int t = tid; t < 1260; t += TPB) w3s[t] = W3[t];
    for (int t = tid; t < 45; t += TPB) b3s[t] = b3[t];
    if (tid < 4) flags[tid] = 0;
    __syncthreads();

    if (wid < 4) {
        // ================= producers: FPS1 (waves 0-3, tid 0..255) =================
        float px[8], py[8], pz[8], mind[8];
#pragma unroll
        for (int k = 0; k < 8; ++k) {
            int j = tid + (k << 8);
            bool v = j < NPTS;
            int jc = v ? j : 0;
            px[k] = v ? sx[jc] : 1e18f;
            py[k] = v ? sy[jc] : 1e18f;
            pz[k] = v ? sz[jc] : 1e18f;
            mind[k] = v ? 1e10f : -1.0f;
        }

        float qx = sx[0], qy = sy[0], qz = sz[0];
        for (int it = 0; it < M1C; ++it) {
            if (tid == 0) { smpx[it] = qx; smpy[it] = qy; smpz[it] = qz; }
            float m[8];
#pragma unroll
            for (int k = 0; k < 8; ++k) {
                float d = dist3(px[k], py[k], pz[k], qx, qy, qz);
                m[k] = fminf(mind[k], d);
                mind[k] = m[k];
            }
            // tree argmax over 8 chunks; strict > keeps lowest chunk on ties
            float va = m[0]; int ka = 0; if (m[1] > va) { va = m[1]; ka = 1; }
            float vb = m[2]; int kb = 2; if (m[3] > vb) { vb = m[3]; kb = 3; }
            float vc = m[4]; int kc = 4; if (m[5] > vc) { vc = m[5]; kc = 5; }
            float vd = m[6]; int kd = 6; if (m[7] > vd) { vd = m[7]; kd = 7; }
            if (vb > va) { va = vb; ka = kb; }
            if (vd > vc) { vc = vd; kc = kd; }
            if (vc > va) { va = vc; ka = kc; }
            float bv = va; int bi = tid + (ka << 8);
            if (it == M1C - 1) {
                if (lane == 0)
                    __hip_atomic_store(&flags[wid], M1C, __ATOMIC_RELEASE,
                                       __HIP_MEMORY_SCOPE_WORKGROUP);
                break;
            }
            float lv = bv; int li = bi;
            wave_argmax(bv, bi);
            int p = it & 1;
            if (lv == bv && li == bi) {            // unique winner lane per wave
                int k = bi >> 8;
                float cx = px[0], cy = py[0], cz = pz[0];
#pragma unroll
                for (int kk = 1; kk < 8; ++kk) {
                    bool t = (k == kk);
                    cx = t ? px[kk] : cx;
                    cy = t ? py[kk] : cy;
                    cz = t ? pz[kk] : cz;
                }
                sA[p][wid] = make_float4(bv, __int_as_float(bi), cx, cy);
                sZ[p][wid] = cz;
            }
            if (lane == 0)
                __hip_atomic_store(&flags[wid], it + 1, __ATOMIC_RELEASE,
                                   __HIP_MEMORY_SCOPE_WORKGROUP);
            // spin (with backoff) until all 4 producer waves posted this iteration
            for (;;) {
                int f = 0x7fffffff;
                if (lane < 4)
                    f = __hip_atomic_load(&flags[lane], __ATOMIC_ACQUIRE,
                                          __HIP_MEMORY_SCOPE_WORKGROUP);
                if (__ballot(f >= it + 1) == ~0ull) break;
                __builtin_amdgcn_s_sleep(1);
            }
            float4 a0 = sA[p][0], a1 = sA[p][1], a2 = sA[p][2], a3 = sA[p][3];
            float4 z0 = *(const float4*)&sZ[p][0];
            // tree combine, min-index ties
            float cv0 = a0.x; int ci0 = __float_as_int(a0.y);
            float x0 = a0.z, y0 = a0.w, zz0 = z0.x;
            {
                int ii = __float_as_int(a1.y);
                bool t = (a1.x > cv0) || (a1.x == cv0 && ii < ci0);
                if (t) { cv0 = a1.x; ci0 = ii; x0 = a1.z; y0 = a1.w; zz0 = z0.y; }
            }
            float cv1 = a2.x; int ci1 = __float_as_int(a2.y);
            float x1 = a2.z, y1 = a2.w, zz1 = z0.z;
            {
                int ii = __float_as_int(a3.y);
                bool t = (a3.x > cv1) || (a3.x == cv1 && ii < ci1);
                if (t) { cv1 = a3.x; ci1 = ii; x1 = a3.z; y1 = a3.w; zz1 = z0.w; }
            }
            bool t = (cv1 > cv0) || (cv1 == cv0 && ci1 < ci0);
            qx = t ? x1 : x0; qy = t ? y1 : y0; qz = t ? zz1 : zz0;
        }

        if (wid == 0) {
            // ---- FPS2: 5 from 100 (single wave, in-LDS smp) ----
            float ax = smpx[lane], ay = smpy[lane], az = smpz[lane];
            bool vb2 = lane < (M1C - 64);
            float bx2 = vb2 ? smpx[lane + 64] : 1e18f;
            float by2 = vb2 ? smpy[lane + 64] : 1e18f;
            float bz2 = vb2 ? smpz[lane + 64] : 1e18f;
            float m2a = 1e10f;
            float m2b = vb2 ? 1e10f : -1.0f;
            int last2 = 0;
            for (int it = 0; it < M2C; ++it) {
                float fx = smpx[last2], fy = smpy[last2], fz = smpz[last2];
                if (lane == 0) { s2x[it] = fx; s2y[it] = fy; s2z[it] = fz; }
                m2a = fminf(m2a, dist3(ax, ay, az, fx, fy, fz));
                m2b = fminf(m2b, dist3(bx2, by2, bz2, fx, fy, fz));
                float v = m2a; int i = lane;
                if (m2b > v) { v = m2b; i = lane + 64; }
                wave_argmax(v, i);
                last2 = i;
            }
        }
    } else {
        // ================= consumers: knn1 + MLP1 (waves 4-7) =================
        float rw1[15], rb1[5];
#pragma unroll
        for (int i = 0; i < 15; ++i) rw1[i] = W1[i];
#pragma unroll
        for (int i = 0; i < 5; ++i) rb1[i] = b1[i];

        for (int s = wid - 4; s < M1C; s += 4) {
            // wait until producer wave 0 has published smp[s]
            while (__hip_atomic_load(&flags[0], __ATOMIC_ACQUIRE,
                                     __HIP_MEMORY_SCOPE_WORKGROUP) <= s)
                __builtin_amdgcn_s_sleep(2);
            float qx = smpx[s], qy = smpy[s], qz = smpz[s];
            int cn = 0;
#pragma unroll 4
            for (int c = 0; c < 32; ++c) {
                int j = c * 64 + lane;
                float d = 0.0f; bool pred = false;
                if (j < NPTS) {
                    d = dist3(sx[j], sy[j], sz[j], qx, qy, qz);
                    pred = (d <= R1SQ);
                }
                unsigned long long mb = __ballot(pred);
                if (pred) {
                    int pos = cn + (int)__popcll(mb & ((1ull << lane) - 1ull));
                    if (pos < CANDCAP) { knd[wid][pos] = d; kni[wid][pos] = j; }
                }
                cn += (int)__popcll(mb);
            }
            if (cn > CANDCAP) cn = CANDCAP;  // P(Poisson λ≈14 > 128) ~ 1e-68
            float fmx[5];
#pragma unroll
            for (int f = 0; f < 5; ++f) fmx[f] = -1e30f;
            for (int t = lane; t < cn; t += 64) {
                float d = knd[wid][t]; int j = kni[wid][t];
                bool valid = true;
                if (cn > KNN) {
                    int rank = 0;
                    for (int u = 0; u < cn; ++u) {
                        float du = knd[wid][u]; int iu = kni[wid][u];
                        rank += (du < d || (du == d && iu < j)) ? 1 : 0;
                    }
                    valid = rank < KNN;   // replicates top_k stability (ties -> lower idx)
                }
                if (valid) {
                    float rx = (sx[j] - qx) * INVR1;
                    float ry = (sy[j] - qy) * INVR1;
                    float rz = (sz[j] - qz) * INVR1;
#pragma unroll
                    for (int f = 0; f < 5; ++f) {
                        float h = fmaf(rx, rw1[f], fmaf(ry, rw1[5 + f], fmaf(rz, rw1[10 + f], rb1[f])));
                        fmx[f] = fmaxf(fmx[f], fmaxf(h, 0.0f));
                    }
                }
            }
#pragma unroll
            for (int f = 0; f < 5; ++f) fmx[f] = wave_fmax(fmx[f]);
            if (lane == 0) {
#pragma unroll
                for (int f = 0; f < 5; ++f) f1s[s][f] = fmx[f];
            }
        }
    }
    __syncthreads();   // all 8 waves reach exactly once

    // ================= tail: knn2 + MLP2 (DPP-free), MLP3, decoder =================
    for (int s = wid; s < M2C; s += NW) {
        float qx2 = s2x[s], qy2 = s2y[s], qz2 = s2z[s];
        int cn = 0;
#pragma unroll
        for (int c = 0; c < 2; ++c) {
            int j = c * 64 + lane;
            float d = 0.0f; bool pred = false;
            if (j < M1C) {
                d = dist3(smpx[j], smpy[j], smpz[j], qx2, qy2, qz2);
                pred = (d <= R2SQ);
            }
            unsigned long long mb = __ballot(pred);
            if (pred) {
                int pos = cn + (int)__popcll(mb & ((1ull << lane) - 1ull));
                knd[wid][pos] = d; kni[wid][pos] = j;   // cn<=100<CANDCAP
            }
            cn += (int)__popcll(mb);
        }
        // build valid-candidate input vectors (order-independent for max)
        int nv = 0;
#pragma unroll
        for (int c = 0; c < 2; ++c) {
            int t = c * 64 + lane;
            bool valid = false;
            float in8[8];
            if (t < cn) {
                float d = knd[wid][t]; int j = kni[wid][t];
                valid = true;
                if (cn > KNN) {
                    int rank = 0;
                    for (int u = 0; u < cn; ++u) {
                        float du = knd[wid][u]; int iu = kni[wid][u];
                        rank += (du < d || (du == d && iu < j)) ? 1 : 0;
                    }
                    valid = rank < KNN;
                }
                if (valid) {
                    in8[0] = smpx[j] - qx2; in8[1] = smpy[j] - qy2; in8[2] = smpz[j] - qz2;
#pragma unroll
                    for (int f = 0; f < 5; ++f) in8[3 + f] = f1s[j][f];
                }
            }
            unsigned long long mb = __ballot(valid);
            if (valid) {
                int pos = nv + (int)__popcll(mb & ((1ull << lane) - 1ull));
#pragma unroll
                for (int i = 0; i < 8; ++i) vin[s][pos][i] = in8[i];   // nv<=20
            }
            nv += (int)__popcll(mb);
        }
        // feature-per-lane max (no DPP chains); nv >= 1 (sample in own ball)
        if (lane < 25) {
            float hmx = -1e30f;
            for (int c = 0; c < nv; ++c) {
                float h = b2s[lane];
#pragma unroll
                for (int i = 0; i < 8; ++i) h = fmaf(vin[s][c][i], w2s[i * 25 + lane], h);
                hmx = fmaxf(hmx, fmaxf(h, 0.0f));
            }
            f2s[s][lane] = hmx;
        }
    }
    __syncthreads();

    // ---- MLP3 + max-pool -> latent (45) ----
    if (wid == 0 && lane < 45) {
        float lm = -1e30f;
        for (int r = 0; r < M2C; ++r) {
            float h = b3s[lane];
            h = fmaf(s2x[r] * 0.5f, w3s[0 * 45 + lane], h);
            h = fmaf(s2y[r] * 0.5f, w3s[1 * 45 + lane], h);
            h = fmaf(s2z[r] * 0.5f, w3s[2 * 45 + lane], h);
#pragma unroll
            for (int i = 0; i < 25; ++i) h = fmaf(f2s[r][i], w3s[(3 + i) * 45 + lane], h);
            lm = fmaxf(lm, fmaxf(h, 0.0f));
        }
        latent[lane] = lm;
    }
    __syncthreads();

    // ---- decoder stage 1: latent @ D1 + bD1 -> (5, 28) ----
    for (int t = tid; t < 140; t += TPB) {
        float acc = bD1[t];
        for (int i = 0; i < 45; i++) acc = fmaf(latent[i], D1[i * 140 + t], acc);
        int r = t / 28, c = t % 28;
        if (c < 3) decv[r][c] = acc;
        else cfs[r][c - 3] = fmaxf(acc, 0.0f);
    }
    __syncthreads();

    // ---- decoder stage 2: cf @ D2 + bD2 -> (100, 8) ----
    for (int t = tid; t < 800; t += TPB) {
        int r = t / 160, c = t % 160;
        float acc = bD2[c];
        for (int i = 0; i < 25; i++) acc = fmaf(cfs[r][i], D2[i * 160 + c], acc);
        int g = r * 20 + c / 8, c8 = c % 8;
        if (c8 < 3) dec2s[g][c8] = acc;
        else cf2s[g][c8 - 3] = fmaxf(acc, 0.0f);
    }
    __syncthreads();

    // ---- decoder stage 3 + compose output ----
    float* outb = out + (size_t)b * (NPTS * 3);
    for (int t = tid; t < NPTS * 3; t += TPB) {
        int n = t / 3, c = t % 3;
        int g = n / 20;
        int m = n / 400;
        int r60 = (n % 20) * 3 + c;
        float acc = bD3[r60];
        for (int i = 0; i < 5; i++) acc = fmaf(cf2s[g][i], D3[i * 60 + r60], acc);
        // out = ((dec*R3 + dec2)*R2 + dec3)*R1, R2 = 1
        float val = ((decv[m][c] * 2.0f + dec2s[g][c]) + acc) * 0.3f;
        outb[t] = val;
    }
}

extern "C" void kernel_launch(void* const* d_in, const int* in_sizes, int n_in,
                              void* d_out, int out_size, void* d_ws, size_t ws_size,
                              hipStream_t stream) {
    const float* P   = (const float*)d_in[0];
    const float* W1  = (const float*)d_in[1];
    const float* b1  = (const float*)d_in[2];
    const float* W2  = (const float*)d_in[3];
    const float* b2  = (const float*)d_in[4];
    const float* W3  = (const float*)d_in[5];
    const float* b3  = (const float*)d_in[6];
    const float* D1  = (const float*)d_in[7];
    const float* bD1 = (const float*)d_in[8];
    const float* D2  = (const float*)d_in[9];
    const float* bD2 = (const float*)d_in[10];
    const float* D3  = (const float*)d_in[11];
    const float* bD3 = (const float*)d_in[12];
    float* out = (float*)d_out;

    int B = in_sizes[0] / (NPTS * 3);
    hipLaunchKernelGGL(fused_kernel, dim3(B), dim3(TPB), 0, stream,
                       P, W1, b1, W2, b2, W3, b3, D1, bD1, D2, bD2, D3, bD3, out);
}

// Round 11
// 187.363 us; speedup vs baseline: 1.1452x; 1.0285x over previous
//
#include <hip/hip_runtime.h>

#define TPB 512
#define NW 8
#define NPTS 2000
#define M1C 100
#define M2C 5
#define KNN 20
#define CANDCAP 128

typedef float v2f __attribute__((ext_vector_type(2)));

// Bitwise-exact squared distance matching numpy fp32 sequential sum:
// ((dx*dx + dy*dy) + dz*dz), no FMA contraction.
__device__ __forceinline__ float dist3(float px, float py, float pz,
                                       float qx, float qy, float qz) {
#pragma clang fp contract(off)
    float dx = px - qx, dy = py - qy, dz = pz - qz;
    return dx * dx + dy * dy + dz * dz;
}

// Packed pair variant: identical per-component op order (sub,mul,add,add),
// so each component is bitwise identical to dist3. Lets the compiler emit
// v_pk_add/mul_f32 (VOP3P) to halve issue count.
__device__ __forceinline__ v2f dist3p(v2f px, v2f py, v2f pz, v2f q0, v2f q1, v2f q2) {
#pragma clang fp contract(off)
    v2f dx = px - q0, dy = py - q1, dz = pz - q2;
    v2f ax = dx * dx;
    v2f ay = dy * dy;
    v2f az = dz * dz;
    return (ax + ay) + az;
}

// Fused wave64 (value,index) argmax, min-index tie-break, DPP chain.
#define ARGMAX_STEP(ctrl, rm)                                                        \
    do {                                                                             \
        float ov = __int_as_float(__builtin_amdgcn_update_dpp(                       \
            (int)0xff800000, __float_as_int(v), ctrl, rm, 0xf, false));              \
        int oi = __builtin_amdgcn_update_dpp(0x7fffffff, i, ctrl, rm, 0xf, false);   \
        bool take = (ov > v) || (ov == v && oi < i);                                 \
        v = take ? ov : v;                                                           \
        i = take ? oi : i;                                                           \
    } while (0)

__device__ __forceinline__ void wave_argmax(float& v, int& i) {
    ARGMAX_STEP(0x111, 0xf);
    ARGMAX_STEP(0x112, 0xf);
    ARGMAX_STEP(0x114, 0xf);
    ARGMAX_STEP(0x118, 0xf);
    ARGMAX_STEP(0x142, 0xa);
    ARGMAX_STEP(0x143, 0xc);
    v = __int_as_float(__builtin_amdgcn_readlane(__float_as_int(v), 63));
    i = __builtin_amdgcn_readlane(i, 63);
}

#define FMAX_STEP(ctrl, rm)                                                          \
    do {                                                                             \
        float _t = __int_as_float(__builtin_amdgcn_update_dpp(                       \
            (int)0xff800000, __float_as_int(x), ctrl, rm, 0xf, false));              \
        x = fmaxf(x, _t);                                                            \
    } while (0)

__device__ __forceinline__ float wave_fmax(float x) {
    FMAX_STEP(0x111, 0xf);
    FMAX_STEP(0x112, 0xf);
    FMAX_STEP(0x114, 0xf);
    FMAX_STEP(0x118, 0xf);
    FMAX_STEP(0x142, 0xa);
    FMAX_STEP(0x143, 0xc);
    return __int_as_float(__builtin_amdgcn_readlane(__float_as_int(x), 63));
}

// ============ Fused kernel: FPS producers + knn1/MLP1 consumers + tail ============
// R11 = R10 (best, 121us) + packed-pair producer dist + counter arrival.
__global__ __launch_bounds__(TPB, 2) void fused_kernel(
    const float* __restrict__ P,
    const float* __restrict__ W1, const float* __restrict__ b1,
    const float* __restrict__ W2, const float* __restrict__ b2,
    const float* __restrict__ W3, const float* __restrict__ b3,
    const float* __restrict__ D1, const float* __restrict__ bD1,
    const float* __restrict__ D2, const float* __restrict__ bD2,
    const float* __restrict__ D3, const float* __restrict__ bD3,
    float* __restrict__ out)
{
    __shared__ float sx[NPTS], sy[NPTS], sz[NPTS];
    __shared__ float smpx[M1C], smpy[M1C], smpz[M1C];
    __shared__ float s2x[M2C], s2y[M2C], s2z[M2C];
    __shared__ float f1s[M1C][5];
    __shared__ float knd[NW][CANDCAP];
    __shared__ int   kni[NW][CANDCAP];
    __shared__ float vin[M2C][KNN][8];     // knn2 valid-candidate inputs
    __shared__ __align__(16) float4 sA[2][4];
    __shared__ __align__(16) float  sZ[2][4];
    __shared__ int cnt;                    // monotone arrival counter (4 per FPS iter)
    __shared__ float f2s[M2C][25];
    __shared__ float latent[45];
    __shared__ float decv[M2C][3];
    __shared__ float cfs[M2C][25];
    __shared__ float dec2s[M1C][3];
    __shared__ float cf2s[M1C][5];
    __shared__ float w2s[200], b2s[25], w3s[1260], b3s[45];

    const int b = blockIdx.x;
    const int tid = threadIdx.x;
    const int lane = tid & 63;
    const int wid = tid >> 6;

    const float R1SQ = (float)(0.3 * 0.3);   // f64 product then cast
    const float R2SQ = 1.0f;
    const float INVR1 = 1.0f / 0.3f;

    // ---- staging (all 8 waves): conflict-free stride-1 LDS writes ----
    const float* Pb = P + (size_t)b * (NPTS * 3);
    for (int j = tid; j < NPTS; j += TPB) {
        sx[j] = Pb[3 * j + 0];
        sy[j] = Pb[3 * j + 1];
        sz[j] = Pb[3 * j + 2];
    }
    for (int t = tid; t < 200; t += TPB) w2s[t] = W2[t];
    for (int t = tid; t < 25; t += TPB) b2s[t] = b2[t];
    for (int t = tid; t < 1260; t += TPB) w3s[t] = W3[t];
    for (int t = tid; t < 45; t += TPB) b3s[t] = b3[t];
    if (tid == 0) cnt = 0;
    __syncthreads();

    if (wid < 4) {
        // ================= producers: FPS1 (waves 0-3, tid 0..255) =================
        v2f px2[4], py2[4], pz2[4], mind2[4];
#pragma unroll
        for (int p = 0; p < 4; ++p) {
#pragma unroll
            for (int h = 0; h < 2; ++h) {
                int k = 2 * p + h;
                int j = tid + (k << 8);
                bool v = j < NPTS;
                int jc = v ? j : 0;
                px2[p][h] = v ? sx[jc] : 1e18f;
                py2[p][h] = v ? sy[jc] : 1e18f;
                pz2[p][h] = v ? sz[jc] : 1e18f;
                mind2[p][h] = v ? 1e10f : -1.0f;
            }
        }

        float qx = sx[0], qy = sy[0], qz = sz[0];
        for (int it = 0; it < M1C; ++it) {
            if (tid == 0) { smpx[it] = qx; smpy[it] = qy; smpz[it] = qz; }
            v2f q0 = {qx, qx}, q1 = {qy, qy}, q2 = {qz, qz};
            float m[8];
#pragma unroll
            for (int p = 0; p < 4; ++p) {
                v2f d = dist3p(px2[p], py2[p], pz2[p], q0, q1, q2);
                v2f mm;
                mm[0] = fminf(mind2[p][0], d[0]);
                mm[1] = fminf(mind2[p][1], d[1]);
                mind2[p] = mm;
                m[2 * p] = mm[0];
                m[2 * p + 1] = mm[1];
            }
            // tree argmax over 8 chunks; strict > keeps lowest chunk on ties
            float va = m[0]; int ka = 0; if (m[1] > va) { va = m[1]; ka = 1; }
            float vb = m[2]; int kb = 2; if (m[3] > vb) { vb = m[3]; kb = 3; }
            float vc = m[4]; int kc = 4; if (m[5] > vc) { vc = m[5]; kc = 5; }
            float vd = m[6]; int kd = 6; if (m[7] > vd) { vd = m[7]; kd = 7; }
            if (vb > va) { va = vb; ka = kb; }
            if (vd > vc) { vc = vd; kc = kd; }
            if (vc > va) { va = vc; ka = kc; }
            float bv = va; int bi = tid + (ka << 8);
            if (it == M1C - 1) {
                if (lane == 0)
                    __hip_atomic_fetch_add(&cnt, 1, __ATOMIC_RELEASE,
                                           __HIP_MEMORY_SCOPE_WORKGROUP);
                break;
            }
            float lv = bv; int li = bi;
            wave_argmax(bv, bi);
            int p = it & 1;
            if (lv == bv && li == bi) {            // unique winner lane per wave
                int k = bi >> 8;
                float cx = px2[0][0], cy = py2[0][0], cz = pz2[0][0];
#pragma unroll
                for (int kk = 1; kk < 8; ++kk) {
                    bool t = (k == kk);
                    cx = t ? px2[kk >> 1][kk & 1] : cx;
                    cy = t ? py2[kk >> 1][kk & 1] : cy;
                    cz = t ? pz2[kk >> 1][kk & 1] : cz;
                }
                sA[p][wid] = make_float4(bv, __int_as_float(bi), cx, cy);
                sZ[p][wid] = cz;
            }
            if (lane == 0)
                __hip_atomic_fetch_add(&cnt, 1, __ATOMIC_RELEASE,
                                       __HIP_MEMORY_SCOPE_WORKGROUP);
            // spin until all 4 producer waves posted this iteration
            int need = 4 * (it + 1);
            for (;;) {
                int c = __hip_atomic_load(&cnt, __ATOMIC_ACQUIRE,
                                          __HIP_MEMORY_SCOPE_WORKGROUP);
                if (c >= need) break;
                __builtin_amdgcn_s_sleep(1);
            }
            float4 a0 = sA[p][0], a1 = sA[p][1], a2 = sA[p][2], a3 = sA[p][3];
            float4 z0 = *(const float4*)&sZ[p][0];
            // tree combine, min-index ties
            float cv0 = a0.x; int ci0 = __float_as_int(a0.y);
            float x0 = a0.z, y0 = a0.w, zz0 = z0.x;
            {
                int ii = __float_as_int(a1.y);
                bool t = (a1.x > cv0) || (a1.x == cv0 && ii < ci0);
                if (t) { cv0 = a1.x; ci0 = ii; x0 = a1.z; y0 = a1.w; zz0 = z0.y; }
            }
            float cv1 = a2.x; int ci1 = __float_as_int(a2.y);
            float x1 = a2.z, y1 = a2.w, zz1 = z0.z;
            {
                int ii = __float_as_int(a3.y);
                bool t = (a3.x > cv1) || (a3.x == cv1 && ii < ci1);
                if (t) { cv1 = a3.x; ci1 = ii; x1 = a3.z; y1 = a3.w; zz1 = z0.w; }
            }
            bool t = (cv1 > cv0) || (cv1 == cv0 && ci1 < ci0);
            qx = t ? x1 : x0; qy = t ? y1 : y0; qz = t ? zz1 : zz0;
        }

        if (wid == 0) {
            // ---- FPS2: 5 from 100 (single wave, in-LDS smp) ----
            float ax = smpx[lane], ay = smpy[lane], az = smpz[lane];
            bool vb2 = lane < (M1C - 64);
            float bx2 = vb2 ? smpx[lane + 64] : 1e18f;
            float by2 = vb2 ? smpy[lane + 64] : 1e18f;
            float bz2 = vb2 ? smpz[lane + 64] : 1e18f;
            float m2a = 1e10f;
            float m2b = vb2 ? 1e10f : -1.0f;
            int last2 = 0;
            for (int it = 0; it < M2C; ++it) {
                float fx = smpx[last2], fy = smpy[last2], fz = smpz[last2];
                if (lane == 0) { s2x[it] = fx; s2y[it] = fy; s2z[it] = fz; }
                m2a = fminf(m2a, dist3(ax, ay, az, fx, fy, fz));
                m2b = fminf(m2b, dist3(bx2, by2, bz2, fx, fy, fz));
                float v = m2a; int i = lane;
                if (m2b > v) { v = m2b; i = lane + 64; }
                wave_argmax(v, i);
                last2 = i;
            }
        }
    } else {
        // ================= consumers: knn1 + MLP1 (waves 4-7) =================
        float rw1[15], rb1[5];
#pragma unroll
        for (int i = 0; i < 15; ++i) rw1[i] = W1[i];
#pragma unroll
        for (int i = 0; i < 5; ++i) rb1[i] = b1[i];

        for (int s = wid - 4; s < M1C; s += 4) {
            // wait until all producers finished iteration s (smp[s] published)
            while (__hip_atomic_load(&cnt, __ATOMIC_ACQUIRE,
                                     __HIP_MEMORY_SCOPE_WORKGROUP) < 4 * (s + 1))
                __builtin_amdgcn_s_sleep(2);
            float qx = smpx[s], qy = smpy[s], qz = smpz[s];
            int cn = 0;
#pragma unroll 4
            for (int c = 0; c < 32; ++c) {
                int j = c * 64 + lane;
                float d = 0.0f; bool pred = false;
                if (j < NPTS) {
                    d = dist3(sx[j], sy[j], sz[j], qx, qy, qz);
                    pred = (d <= R1SQ);
                }
                unsigned long long mb = __ballot(pred);
                if (pred) {
                    int pos = cn + (int)__popcll(mb & ((1ull << lane) - 1ull));
                    if (pos < CANDCAP) { knd[wid][pos] = d; kni[wid][pos] = j; }
                }
                cn += (int)__popcll(mb);
            }
            if (cn > CANDCAP) cn = CANDCAP;  // P(Poisson λ≈14 > 128) ~ 1e-68
            float fmx[5];
#pragma unroll
            for (int f = 0; f < 5; ++f) fmx[f] = -1e30f;
            for (int t = lane; t < cn; t += 64) {
                float d = knd[wid][t]; int j = kni[wid][t];
                bool valid = true;
                if (cn > KNN) {
                    int rank = 0;
                    for (int u = 0; u < cn; ++u) {
                        float du = knd[wid][u]; int iu = kni[wid][u];
                        rank += (du < d || (du == d && iu < j)) ? 1 : 0;
                    }
                    valid = rank < KNN;   // replicates top_k stability (ties -> lower idx)
                }
                if (valid) {
                    float rx = (sx[j] - qx) * INVR1;
                    float ry = (sy[j] - qy) * INVR1;
                    float rz = (sz[j] - qz) * INVR1;
#pragma unroll
                    for (int f = 0; f < 5; ++f) {
                        float h = fmaf(rx, rw1[f], fmaf(ry, rw1[5 + f], fmaf(rz, rw1[10 + f], rb1[f])));
                        fmx[f] = fmaxf(fmx[f], fmaxf(h, 0.0f));
                    }
                }
            }
#pragma unroll
            for (int f = 0; f < 5; ++f) fmx[f] = wave_fmax(fmx[f]);
            if (lane == 0) {
#pragma unroll
                for (int f = 0; f < 5; ++f) f1s[s][f] = fmx[f];
            }
        }
    }
    __syncthreads();   // all 8 waves reach exactly once

    // ================= tail: knn2 + MLP2 (DPP-free), MLP3, decoder =================
    for (int s = wid; s < M2C; s += NW) {
        float qx2 = s2x[s], qy2 = s2y[s], qz2 = s2z[s];
        int cn = 0;
#pragma unroll
        for (int c = 0; c < 2; ++c) {
            int j = c * 64 + lane;
            float d = 0.0f; bool pred = false;
            if (j < M1C) {
                d = dist3(smpx[j], smpy[j], smpz[j], qx2, qy2, qz2);
                pred = (d <= R2SQ);
            }
            unsigned long long mb = __ballot(pred);
            if (pred) {
                int pos = cn + (int)__popcll(mb & ((1ull << lane) - 1ull));
                knd[wid][pos] = d; kni[wid][pos] = j;   // cn<=100<CANDCAP
            }
            cn += (int)__popcll(mb);
        }
        // build valid-candidate input vectors (order-independent for max)
        int nv = 0;
#pragma unroll
        for (int c = 0; c < 2; ++c) {
            int t = c * 64 + lane;
            bool valid = false;
            float in8[8];
            if (t < cn) {
                float d = knd[wid][t]; int j = kni[wid][t];
                valid = true;
                if (cn > KNN) {
                    int rank = 0;
                    for (int u = 0; u < cn; ++u) {
                        float du = knd[wid][u]; int iu = kni[wid][u];
                        rank += (du < d || (du == d && iu < j)) ? 1 : 0;
                    }
                    valid = rank < KNN;
                }
                if (valid) {
                    in8[0] = smpx[j] - qx2; in8[1] = smpy[j] - qy2; in8[2] = smpz[j] - qz2;
#pragma unroll
                    for (int f = 0; f < 5; ++f) in8[3 + f] = f1s[j][f];
                }
            }
            unsigned long long mb = __ballot(valid);
            if (valid) {
                int pos = nv + (int)__popcll(mb & ((1ull << lane) - 1ull));
#pragma unroll
                for (int i = 0; i < 8; ++i) vin[s][pos][i] = in8[i];   // nv<=20
            }
            nv += (int)__popcll(mb);
        }
        // feature-per-lane max (no DPP chains); nv >= 1 (sample in own ball)
        if (lane < 25) {
            float hmx = -1e30f;
            for (int c = 0; c < nv; ++c) {
                float h = b2s[lane];
#pragma unroll
                for (int i = 0; i < 8; ++i) h = fmaf(vin[s][c][i], w2s[i * 25 + lane], h);
                hmx = fmaxf(hmx, fmaxf(h, 0.0f));
            }
            f2s[s][lane] = hmx;
        }
    }
    __syncthreads();

    // ---- MLP3 + max-pool -> latent (45) ----
    if (wid == 0 && lane < 45) {
        float lm = -1e30f;
        for (int r = 0; r < M2C; ++r) {
            float h = b3s[lane];
            h = fmaf(s2x[r] * 0.5f, w3s[0 * 45 + lane], h);
            h = fmaf(s2y[r] * 0.5f, w3s[1 * 45 + lane], h);
            h = fmaf(s2z[r] * 0.5f, w3s[2 * 45 + lane], h);
#pragma unroll
            for (int i = 0; i < 25; ++i) h = fmaf(f2s[r][i], w3s[(3 + i) * 45 + lane], h);
            lm = fmaxf(lm, fmaxf(h, 0.0f));
        }
        latent[lane] = lm;
    }
    __syncthreads();

    // ---- decoder stage 1: latent @ D1 + bD1 -> (5, 28) ----
    for (int t = tid; t < 140; t += TPB) {
        float acc = bD1[t];
        for (int i = 0; i < 45; i++) acc = fmaf(latent[i], D1[i * 140 + t], acc);
        int r = t / 28, c = t % 28;
        if (c < 3) decv[r][c] = acc;
        else cfs[r][c - 3] = fmaxf(acc, 0.0f);
    }
    __syncthreads();

    // ---- decoder stage 2: cf @ D2 + bD2 -> (100, 8) ----
    for (int t = tid; t < 800; t += TPB) {
        int r = t / 160, c = t % 160;
        float acc = bD2[c];
        for (int i = 0; i < 25; i++) acc = fmaf(cfs[r][i], D2[i * 160 + c], acc);
        int g = r * 20 + c / 8, c8 = c % 8;
        if (c8 < 3) dec2s[g][c8] = acc;
        else cf2s[g][c8 - 3] = fmaxf(acc, 0.0f);
    }
    __syncthreads();

    // ---- decoder stage 3 + compose output ----
    float* outb = out + (size_t)b * (NPTS * 3);
    for (int t = tid; t < NPTS * 3; t += TPB) {
        int n = t / 3, c = t % 3;
        int g = n / 20;
        int m = n / 400;
        int r60 = (n % 20) * 3 + c;
        float acc = bD3[r60];
        for (int i = 0; i < 5; i++) acc = fmaf(cf2s[g][i], D3[i * 60 + r60], acc);
        // out = ((dec*R3 + dec2)*R2 + dec3)*R1, R2 = 1
        float val = ((decv[m][c] * 2.0f + dec2s[g][c]) + acc) * 0.3f;
        outb[t] = val;
    }
}

extern "C" void kernel_launch(void* const* d_in, const int* in_sizes, int n_in,
                              void* d_out, int out_size, void* d_ws, size_t ws_size,
                              hipStream_t stream) {
    const float* P   = (const float*)d_in[0];
    const float* W1  = (const float*)d_in[1];
    const float* b1  = (const float*)d_in[2];
    const float* W2  = (const float*)d_in[3];
    const float* b2  = (const float*)d_in[4];
    const float* W3  = (const float*)d_in[5];
    const float* b3  = (const float*)d_in[6];
    const float* D1  = (const float*)d_in[7];
    const float* bD1 = (const float*)d_in[8];
    const float* D2  = (const float*)d_in[9];
    const float* bD2 = (const float*)d_in[10];
    const float* D3  = (const float*)d_in[11];
    const float* bD3 = (const float*)d_in[12];
    float* out = (float*)d_out;

    int B = in_sizes[0] / (NPTS * 3);
    hipLaunchKernelGGL(fused_kernel, dim3(B), dim3(TPB), 0, stream,
                       P, W1, b1, W2, b2, W3, b3, D1, bD1, D2, bD2, D3, bD3, out);
}